// Round 3
// baseline (401.486 us; speedup 1.0000x reference)
//
#include <hip/hip_runtime.h>

typedef unsigned short ushort;
typedef __attribute__((ext_vector_type(8))) short short8;
typedef __attribute__((ext_vector_type(8))) unsigned short ushort8;
typedef __attribute__((ext_vector_type(4))) unsigned short ushort4v;
typedef __attribute__((ext_vector_type(4))) float fx4;

#define MAXNNZ (256*7)

__device__ __forceinline__ ushort f2bf(float f) {
    union { float f; unsigned u; } v; v.f = f;
    unsigned r = v.u + 0x7fffu + ((v.u >> 16) & 1u);
    return (ushort)(r >> 16);
}

__device__ __forceinline__ float bf2f(ushort b) {
    union { unsigned u; float f; } v; v.u = ((unsigned)b) << 16;
    return v.f;
}

// async global->LDS, 16B per lane; LDS dest = wave-uniform base + lane*16
__device__ __forceinline__ void gload_lds16(const ushort* g, ushort* l) {
    __builtin_amdgcn_global_load_lds(
        (const __attribute__((address_space(1))) unsigned int*)g,
        (__attribute__((address_space(3))) unsigned int*)l, 16, 0, 0);
}

// ---------------- top-7 per row of coeff (rows 0..255), emit COO for cols<256 -----
__global__ __launch_bounds__(256)
void topk_kernel(const float* __restrict__ coeff,
                 int* __restrict__ coo_cnt, int* __restrict__ coo_m,
                 int* __restrict__ coo_p, float* __restrict__ coo_v)
{
    int row = blockIdx.x;            // = m index, 0..255
    int tid = threadIdx.x;
    const float* crow = coeff + (long)row * 2048;
    float av[8];
#pragma unroll
    for (int i = 0; i < 8; ++i) av[i] = fabsf(crow[tid + 256 * i]);
    __shared__ unsigned long long red[256];
    for (int t = 0; t < 7; ++t) {
        float mx = -1.f; int mi = 0;
#pragma unroll
        for (int i = 0; i < 8; ++i) if (av[i] > mx) { mx = av[i]; mi = i; }
        unsigned col = (unsigned)(tid + 256 * mi);
        unsigned long long pk = ((unsigned long long)__float_as_uint(mx) << 32)
                              | (unsigned long long)(2048u - col); // tie -> smaller col
        red[tid] = pk; __syncthreads();
        for (int s = 128; s > 0; s >>= 1) {
            if (tid < s) { if (red[tid + s] > red[tid]) red[tid] = red[tid + s]; }
            __syncthreads();
        }
        unsigned long long w = red[0];
        __syncthreads();
        unsigned wcol = 2048u - (unsigned)(w & 0xffffffffu);
        if ((wcol & 255u) == (unsigned)tid) av[wcol >> 8] = -1.f; // consume
        if (tid == 0 && wcol < 256u) {
            int pos = atomicAdd(coo_cnt, 1);
            coo_m[pos] = row; coo_p[pos] = (int)wcol; coo_v[pos] = crow[wcol];
        }
    }
}

// ---------------- COO -> CSC (single block) ----------------
__global__ __launch_bounds__(256)
void csc_kernel(const int* __restrict__ coo_cnt, const int* __restrict__ coo_m,
                const int* __restrict__ coo_p, const float* __restrict__ coo_v,
                int* __restrict__ csc_ptr, int* __restrict__ csc_m, float* __restrict__ csc_v)
{
    __shared__ int cnt[256];
    __shared__ int off[257];
    __shared__ int cur[256];
    int tid = threadIdx.x;
    cnt[tid] = 0;
    __syncthreads();
    int n = *coo_cnt; if (n > MAXNNZ) n = MAXNNZ;
    for (int e = tid; e < n; e += 256) atomicAdd(&cnt[coo_p[e]], 1);
    __syncthreads();
    if (tid == 0) {
        int s = 0;
        for (int p = 0; p < 256; ++p) { off[p] = s; s += cnt[p]; }
        off[256] = s;
    }
    __syncthreads();
    csc_ptr[tid] = off[tid];
    if (tid == 0) csc_ptr[256] = off[256];
    cur[tid] = off[tid];
    __syncthreads();
    for (int e = tid; e < n; e += 256) {
        int p = coo_p[e];
        int pos = atomicAdd(&cur[p], 1);
        csc_m[pos] = coo_m[e];
        csc_v[pos] = coo_v[e];
    }
}

// ---------------- fp32 -> bf16 convert, 4 tensors in one launch ----------------
__global__ void cvt4_kernel(const float* a0, ushort* d0, int n0,
                            const float* a1, ushort* d1, int n1,
                            const float* a2, ushort* d2, int n2,
                            const float* a3, ushort* d3, int n3)
{
    const float* s; ushort* d; int n;
    switch (blockIdx.y) {
        case 0: s = a0; d = d0; n = n0; break;
        case 1: s = a1; d = d1; n = n1; break;
        case 2: s = a2; d = d2; n = n2; break;
        default: s = a3; d = d3; n = n3; break;
    }
    int nv = n >> 2;
    for (int i = blockIdx.x * blockDim.x + threadIdx.x; i < nv; i += gridDim.x * blockDim.x) {
        fx4 v = ((const fx4*)s)[i];
        ushort4v o;
        o[0] = f2bf(v[0]); o[1] = f2bf(v[1]); o[2] = f2bf(v[2]); o[3] = f2bf(v[3]);
        ((ushort4v*)d)[i] = o;
    }
}

// ---------------- transpose f32 [z][R][C] -> bf16 [z][C][R] ----------------
__global__ __launch_bounds__(256)
void transpose_f32_bf16(const float* __restrict__ in, ushort* __restrict__ out, int R, int C)
{
    int z = blockIdx.z;
    const float* ib = in + (long)z * R * C;
    ushort* ob = out + (long)z * R * C;
    __shared__ ushort tile[64][72];
    int r0 = blockIdx.x * 64, c0 = blockIdx.y * 64;
    int tid = threadIdx.x;
    int rl = tid >> 2, sg = tid & 3;
#pragma unroll
    for (int h = 0; h < 4; ++h) {
        fx4 v = *(const fx4*)(ib + (long)(r0 + rl) * C + c0 + h * 16 + sg * 4);
#pragma unroll
        for (int i = 0; i < 4; ++i) tile[h * 16 + sg * 4 + i][rl] = f2bf(v[i]);
    }
    __syncthreads();
    int cl = rl;
#pragma unroll
    for (int h = 0; h < 2; ++h) {
        ushort8 vv = *(const ushort8*)(&tile[cl][h * 32 + sg * 8]);
        *(ushort8*)(ob + (long)(c0 + cl) * R + r0 + h * 32 + sg * 8) = vv;
    }
}

// ---------------- K-combine: ktc[z][p][d] = sum_e csc_v[e] * kbT[z][m_e][d] --------
__global__ __launch_bounds__(256)
void kcomb_kernel(const ushort* __restrict__ kbT, ushort* __restrict__ ktc,
                  const int* __restrict__ csc_ptr, const int* __restrict__ csc_m,
                  const float* __restrict__ csc_v)
{
    int z = blockIdx.y;
    int tid = threadIdx.x;
    int p = blockIdx.x * 64 + (tid >> 2);
    int d0 = (tid & 3) * 64;
    const ushort* src = kbT + (long)z * 65536;
    float acc[64];
#pragma unroll
    for (int i = 0; i < 64; ++i) acc[i] = 0.f;
    int e0 = csc_ptr[p], e1 = csc_ptr[p + 1];
    for (int e = e0; e < e1; ++e) {
        const ushort* row = src + csc_m[e] * 256 + d0;
        float c = csc_v[e];
#pragma unroll
        for (int u = 0; u < 8; ++u) {
            ushort8 v = *(const ushort8*)(row + u * 8);
#pragma unroll
            for (int t = 0; t < 8; ++t) acc[u * 8 + t] += bf2f(v[t]) * c;
        }
    }
    ushort* dst = ktc + (long)z * 65536 + (long)p * 256 + d0;
#pragma unroll
    for (int u = 0; u < 8; ++u) {
        ushort8 o;
#pragma unroll
        for (int t = 0; t < 8; ++t) o[t] = f2bf(acc[u * 8 + t]);
        *(ushort8*)(dst + u * 8) = o;
    }
}

// ---------------- fused attention: T=QK~^T/s, softmax, O = P V^T ----------------
// One block per z=(b,h), 512 threads, 2 n-halves of 128 rows each.
// P lives in LDS only (XOR-swizzled [128][256] bf16); V double-buffered per 32-p chunk.
// Staging uses linear global_load_lds dest + inverse-swizzled global source (rule #21).
__global__ __launch_bounds__(512)
void attn_kernel(const ushort* __restrict__ Q, const ushort* __restrict__ Kt,
                 const ushort* __restrict__ V, ushort* __restrict__ O,
                 const float* __restrict__ scale_src)
{
    int z = blockIdx.x;              // b*8 + h
    int b = z >> 3, h = z & 7;
    const ushort* Qz = Q + (long)z * 65536;            // [n][d]
    const ushort* Kz = Kt + (long)z * 65536;           // [p][d]
    const ushort* Vz = V + (long)b * 524288 + (long)h * 65536;  // rows d, cols p
    ushort* Ob = O + (long)b * 524288 + (long)h * 256; // [n][2048] slab, cols h*256+d

    __shared__ __align__(16) ushort P[128 * 256];      // 64 KB, doubles as Ct
    __shared__ __align__(16) ushort As[128 * 32];      // 8 KB  (Q chunk)
    __shared__ __align__(16) ushort Bs[256 * 32];      // 16 KB (K~ chunk)
    __shared__ __align__(16) ushort Vst[2][256 * 32];  // 32 KB (V dbuf)
    __shared__ float rmax[4][128];
    __shared__ float rsum[4][128];

    int tid = threadIdx.x;
    int wave = tid >> 6, lane = tid & 63;
    int l16 = lane & 15, quad = lane >> 4;

    // staging: dest slot s covers LDS row s>>2, 16B-chunk s&3; pre-swizzle source
    int skey = (tid >> 3) & 3;                         // = (dest_row>>1)&3
    int scol = ((tid & 3) ^ skey) * 8;
    int srow = tid >> 2;                               // 0..127
    const ushort* qsrc  = Qz + (long)srow * 256 + scol;
    const ushort* ksrc0 = Kz + (long)srow * 256 + scol;
    const ushort* ksrc1 = ksrc0 + 128 * 256;
    const ushort* vsrc0 = Vz + (long)srow * 256 + scol;
    const ushort* vsrc1 = vsrc0 + 128 * 256;
    ushort* aDst  = As + wave * 512;
    ushort* bDst0 = Bs + wave * 512;
    ushort* bDst1 = Bs + 4096 + wave * 512;

    int rk = (l16 >> 1) & 3;                           // read swizzle key (64B rows)
    float sc = 1.0f / scale_src[0];

    for (int hf = 0; hf < 2; ++hf) {
        // ================= phase 1: T tile [128 n][256 p], softmax -> P =========
        int wrow = wave >> 2, wcol = wave & 3;         // 2 x 4 wave grid
        fx4 acc[4][4];
#pragma unroll
        for (int i = 0; i < 4; ++i)
#pragma unroll
            for (int j = 0; j < 4; ++j) acc[i][j] = (fx4){0.f, 0.f, 0.f, 0.f};

        const ushort* qs = qsrc + (long)hf * 128 * 256;
        for (int kc = 0; kc < 256; kc += 32) {
            __syncthreads();
            gload_lds16(qs + kc, aDst);
            gload_lds16(ksrc0 + kc, bDst0);
            gload_lds16(ksrc1 + kc, bDst1);
            __syncthreads();
            short8 af[4], bf[4];
#pragma unroll
            for (int i = 0; i < 4; ++i)
                af[i] = *(const short8*)(As + (wrow * 64 + i * 16 + l16) * 32 + ((quad ^ rk) * 8));
#pragma unroll
            for (int j = 0; j < 4; ++j)
                bf[j] = *(const short8*)(Bs + (wcol * 64 + j * 16 + l16) * 32 + ((quad ^ rk) * 8));
#pragma unroll
            for (int i = 0; i < 4; ++i)
#pragma unroll
                for (int j = 0; j < 4; ++j)
                    acc[i][j] = __builtin_amdgcn_mfma_f32_16x16x32_bf16(af[i], bf[j], acc[i][j], 0, 0, 0);
        }

#pragma unroll
        for (int i = 0; i < 4; ++i)
#pragma unroll
            for (int j = 0; j < 4; ++j)
#pragma unroll
                for (int r = 0; r < 4; ++r) acc[i][j][r] *= sc;

        // row max (local over j, shfl over 16 lanes, LDS over 4 wcol groups)
        float lm[4][4];
#pragma unroll
        for (int i = 0; i < 4; ++i)
#pragma unroll
            for (int r = 0; r < 4; ++r) {
                float m = -1e30f;
#pragma unroll
                for (int j = 0; j < 4; ++j) m = fmaxf(m, acc[i][j][r]);
                lm[i][r] = m;
            }
#pragma unroll
        for (int d = 1; d < 16; d <<= 1)
#pragma unroll
            for (int i = 0; i < 4; ++i)
#pragma unroll
                for (int r = 0; r < 4; ++r) lm[i][r] = fmaxf(lm[i][r], __shfl_xor(lm[i][r], d, 16));
        if (l16 == 0) {
#pragma unroll
            for (int i = 0; i < 4; ++i)
#pragma unroll
                for (int r = 0; r < 4; ++r)
                    rmax[wcol][wrow * 64 + i * 16 + quad * 4 + r] = lm[i][r];
        }
        __syncthreads();

        float ls[4][4];
#pragma unroll
        for (int i = 0; i < 4; ++i)
#pragma unroll
            for (int r = 0; r < 4; ++r) {
                int row = wrow * 64 + i * 16 + quad * 4 + r;
                float M = fmaxf(fmaxf(rmax[0][row], rmax[1][row]),
                                fmaxf(rmax[2][row], rmax[3][row]));
                float s = 0.f;
#pragma unroll
                for (int j = 0; j < 4; ++j) {
                    float e = __expf(acc[i][j][r] - M);
                    acc[i][j][r] = e;
                    s += e;
                }
                ls[i][r] = s;
            }
#pragma unroll
        for (int d = 1; d < 16; d <<= 1)
#pragma unroll
            for (int i = 0; i < 4; ++i)
#pragma unroll
                for (int r = 0; r < 4; ++r) ls[i][r] += __shfl_xor(ls[i][r], d, 16);
        if (l16 == 0) {
#pragma unroll
            for (int i = 0; i < 4; ++i)
#pragma unroll
                for (int r = 0; r < 4; ++r)
                    rsum[wcol][wrow * 64 + i * 16 + quad * 4 + r] = ls[i][r];
        }
        __syncthreads();

        // normalize + write P (swizzled: chunk ^= row&7)
#pragma unroll
        for (int i = 0; i < 4; ++i)
#pragma unroll
            for (int r = 0; r < 4; ++r) {
                int row = wrow * 64 + i * 16 + quad * 4 + r;
                float inv = 1.0f / (rsum[0][row] + rsum[1][row] + rsum[2][row] + rsum[3][row]);
                int key = row & 7;
#pragma unroll
                for (int j = 0; j < 4; ++j) {
                    int p = wcol * 64 + j * 16 + l16;
                    int idx = row * 256 + ((((p >> 3) ^ key) << 3) | (p & 7));
                    P[idx] = f2bf(acc[i][j][r] * inv);
                }
            }
        __syncthreads();

        // ================= phase 2: O[128 n][256 d] = P * V^T ===================
        int r2 = wave >> 2, c2 = wave & 3;             // 2 n-halves x 4 d-quarters
        fx4 acc2[4][4];
#pragma unroll
        for (int i = 0; i < 4; ++i)
#pragma unroll
            for (int j = 0; j < 4; ++j) acc2[i][j] = (fx4){0.f, 0.f, 0.f, 0.f};

        gload_lds16(vsrc0, Vst[0] + wave * 512);
        gload_lds16(vsrc1, Vst[0] + 4096 + wave * 512);
        __syncthreads();

        for (int kk = 0; kk < 8; ++kk) {
            short8 pa[4], vf[4];
#pragma unroll
            for (int i = 0; i < 4; ++i) {
                int row = r2 * 64 + i * 16 + l16;
                pa[i] = *(const short8*)(P + row * 256 + (((kk * 4 + quad) ^ (l16 & 7)) * 8));
            }
#pragma unroll
            for (int j = 0; j < 4; ++j)
                vf[j] = *(const short8*)(Vst[kk & 1] + (c2 * 64 + j * 16 + l16) * 32 + ((quad ^ rk) * 8));
            if (kk < 7) {
                gload_lds16(vsrc0 + (kk + 1) * 32, Vst[(kk + 1) & 1] + wave * 512);
                gload_lds16(vsrc1 + (kk + 1) * 32, Vst[(kk + 1) & 1] + 4096 + wave * 512);
            }
#pragma unroll
            for (int i = 0; i < 4; ++i)
#pragma unroll
                for (int j = 0; j < 4; ++j)
                    acc2[i][j] = __builtin_amdgcn_mfma_f32_16x16x32_bf16(pa[i], vf[j], acc2[i][j], 0, 0, 0);
            __syncthreads();
        }

        // epilogue: re-tile through P buffer (dead), coalesced 512B-row stores
#pragma unroll
        for (int i = 0; i < 4; ++i)
#pragma unroll
            for (int j = 0; j < 4; ++j) {
                int rowb = r2 * 64 + i * 16 + quad * 4;
                int col = c2 * 64 + j * 16 + l16;
#pragma unroll
                for (int rr = 0; rr < 4; ++rr) {
                    int row = rowb + rr;
                    int idx = row * 256 + ((((col >> 3) ^ (row & 7)) << 3) | (col & 7));
                    P[idx] = f2bf(acc2[i][j][rr]);
                }
            }
        __syncthreads();
#pragma unroll
        for (int pass = 0; pass < 8; ++pass) {
            int row = pass * 16 + (tid >> 5), ch = tid & 31;
            ushort8 v = *(const ushort8*)(P + row * 256 + ((ch ^ (row & 7)) << 3));
            *(ushort8*)(Ob + (long)(hf * 128 + row) * 2048 + ch * 8) = v;
        }
        __syncthreads();
    }
}

// ---------------- 256x256-tile NT GEMM, 8 waves, fine-phase pipelined --------------
// 4-deep LDS ring (BK=32), 2 phases per K-tile; counted vmcnt; swizzled LDS.
// MODE 4: merged QKV, A=[6144][512] wqkv, B=[8192][512] xT; sec = m0>>11 uniform.
// MODE 5: final: A=[2048][2048] wob, B=[8192][2048] obT; f32 out + bias (direct).
template<int MODE>
__global__ __launch_bounds__(512, 2)
void gemm256(const ushort* __restrict__ A, const ushort* __restrict__ B,
             void* __restrict__ C,
             const float* __restrict__ bias0, const float* __restrict__ bias1,
             const float* __restrict__ bias2,
             int MT, int K)
{
    __shared__ __align__(16) ushort lds[4][2][8192];   // 128 KiB ring: 4 x (A,B) x 256x32

    int nwg = gridDim.x;
    int bid = blockIdx.x;
    int cpx = nwg >> 3;                        // nwg % 8 == 0 guaranteed by launch
    int swz = (bid & 7) * cpx + (bid >> 3);    // XCD-aware swizzle (bijective)
    int mt = swz % MT, nt = swz / MT;
    int m0 = mt << 8, n0 = nt << 8;

    int tid = threadIdx.x;
    int wave = tid >> 6, lane = tid & 63;
    int wr = wave >> 2, wc = wave & 3;         // 2x4 wave grid; per-wave C = 128x64
    int l16 = lane & 15, quad = lane >> 4;

    int lc = (((lane & 3) ^ ((lane >> 3) & 3))) * 8;
    const ushort* gA0 = A + (long long)(m0 + wave * 16 + (lane >> 2)) * K + lc;
    const ushort* gA1 = gA0 + (long long)128 * K;
    const ushort* gB0 = B + (long long)(n0 + wave * 16 + (lane >> 2)) * K + lc;
    const ushort* gB1 = gB0 + (long long)128 * K;
    int ldso = wave * 512;                     // wave's 1KB stripe (ushorts)

    int rsw = ((l16 >> 1) & 3) * 8;
    int aoff = (wr * 128 + l16) * 32 + ((quad * 8) ^ rsw);
    int boff = (wc * 64 + l16) * 32 + ((quad * 8) ^ rsw);

    fx4 acc[8][4];
#pragma unroll
    for (int i = 0; i < 8; ++i)
#pragma unroll
        for (int j = 0; j < 4; ++j) acc[i][j] = (fx4){0.f, 0.f, 0.f, 0.f};

    auto stageA = [&](int b, int kc) {
        gload_lds16(gA0 + kc, &lds[b][0][ldso]);
        gload_lds16(gA1 + kc, &lds[b][0][4096 + ldso]);
    };
    auto stageB = [&](int b, int kc) {
        gload_lds16(gB0 + kc, &lds[b][1][ldso]);
        gload_lds16(gB1 + kc, &lds[b][1][4096 + ldso]);
    };

    short8 af[4], bf[4];
    auto readA = [&](int b, int half) {
        const ushort* p = &lds[b][0][aoff + half * 2048];
#pragma unroll
        for (int i = 0; i < 4; ++i) af[i] = *(const short8*)(p + i * 512);
    };
    auto readB = [&](int b) {
        const ushort* p = &lds[b][1][boff];
#pragma unroll
        for (int j = 0; j < 4; ++j) bf[j] = *(const short8*)(p + j * 512);
    };
    auto mma = [&](int half) {
        __builtin_amdgcn_s_setprio(1);
#pragma unroll
        for (int i = 0; i < 4; ++i)
#pragma unroll
            for (int j = 0; j < 4; ++j)
                acc[half * 4 + i][j] =
                    __builtin_amdgcn_mfma_f32_16x16x32_bf16(af[i], bf[j], acc[half * 4 + i][j], 0, 0, 0);
        __builtin_amdgcn_s_setprio(0);
    };

    int NT = K >> 5;
    stageA(0, 0);  stageB(0, 0);
    stageA(1, 32); stageB(1, 32);
    stageA(2, 64); stageB(2, 64);
    asm volatile("s_waitcnt vmcnt(8)" ::: "memory");
    __builtin_amdgcn_s_barrier();

    for (int t = 0; t < NT; ++t) {
        int b = t & 3;
        readA(b, 0); readB(b);
        if (t + 3 < NT) stageA((t + 3) & 3, (t + 3) << 5);
        __builtin_amdgcn_s_barrier();
        asm volatile("s_waitcnt lgkmcnt(0)" ::: "memory");
        __builtin_amdgcn_sched_barrier(0);
        mma(0);
        __builtin_amdgcn_s_barrier();
        readA(b, 1);
        if (t + 3 < NT) {
            stageB((t + 3) & 3, (t + 3) << 5);
            asm volatile("s_waitcnt vmcnt(8)" ::: "memory");
        } else if (t + 2 < NT) {
            asm volatile("s_waitcnt vmcnt(4)" ::: "memory");
        } else if (t + 1 < NT) {
            asm volatile("s_waitcnt vmcnt(0)" ::: "memory");
        }
        __builtin_amdgcn_s_barrier();
        asm volatile("s_waitcnt lgkmcnt(0)" ::: "memory");
        __builtin_amdgcn_sched_barrier(0);
        mma(1);
        __builtin_amdgcn_s_barrier();
    }

    if (MODE == 5) {
        float* Cf = (float*)C + (long long)nt * 524288;
#pragma unroll
        for (int i = 0; i < 8; ++i) {
            int m = m0 + wr * 128 + i * 16 + quad * 4;
#pragma unroll
            for (int j = 0; j < 4; ++j) {
                int n = wc * 64 + j * 16 + l16;
                float* dst = Cf + (long long)m * 256 + n;
#pragma unroll
                for (int r = 0; r < 4; ++r)
                    dst[(long)r * 256] = acc[i][j][r] + bias0[m + r];
            }
        }
        return;
    }

    if (MODE == 4) {
        int sec = m0 >> 11;
        int ms0 = m0 & 2047;
        ushort* ct = &lds[0][0][0];            // re-tile buffer: 128 x 264 ushorts
        if (sec < 2) {
            const float* bs = (sec == 0) ? bias0 : bias1;
            ushort* base = (ushort*)C + (long long)sec * 16777216
                         + (long long)nt * 524288 + (long long)(ms0 >> 8) * 65536;
#pragma unroll
            for (int hh = 0; hh < 2; ++hh) {
                if ((wc >> 1) == hh) {
#pragma unroll
                    for (int i = 0; i < 8; ++i)
#pragma unroll
                        for (int j = 0; j < 4; ++j) {
                            int nl = (wc & 1) * 64 + j * 16 + l16;
                            int ml = wr * 128 + i * 16 + quad * 4;
                            ushort4v pk;
#pragma unroll
                            for (int r = 0; r < 4; ++r)
                                pk[r] = f2bf(acc[i][j][r] + bs[ms0 + ml + r]);
                            *(ushort4v*)(ct + nl * 264 + ml) = pk;
                        }
                }
                __syncthreads();
                int row = tid & 127, c0 = (tid >> 7) * 64;
                ushort* dst = base + (long long)(hh * 128 + row) * 256 + c0;
                const ushort* src = ct + row * 264 + c0;
#pragma unroll
                for (int u = 0; u < 8; ++u)
                    *(ushort8*)(dst + u * 8) = *(const ushort8*)(src + u * 8);
                __syncthreads();
            }
        } else {
            ushort* base = (ushort*)C + 33554432LL + (long long)nt * 524288
                         + (long long)ms0 * 256;
#pragma unroll
            for (int hh = 0; hh < 2; ++hh) {
                if (wr == hh) {
#pragma unroll
                    for (int i = 0; i < 8; ++i)
#pragma unroll
                        for (int j = 0; j < 4; ++j) {
                            int nl = wc * 64 + j * 16 + l16;
                            int ml = i * 16 + quad * 4;
#pragma unroll
                            for (int r = 0; r < 4; ++r)
                                ct[(ml + r) * 264 + nl] =
                                    f2bf(acc[i][j][r] + bias2[ms0 + hh * 128 + ml + r]);
                        }
                }
                __syncthreads();
                int row = tid & 127, c0 = (tid >> 7) * 64;
                ushort* dst = base + (long long)(hh * 128 + row) * 256 + c0;
                const ushort* src = ct + row * 264 + c0;
#pragma unroll
                for (int u = 0; u < 8; ++u)
                    *(ushort8*)(dst + u * 8) = *(const ushort8*)(src + u * 8);
                __syncthreads();
            }
        }
        return;
    }
}

extern "C" void kernel_launch(void* const* d_in, const int* in_sizes, int n_in,
                              void* d_out, int out_size, void* d_ws, size_t ws_size,
                              hipStream_t stream)
{
    const float* x     = (const float*)d_in[0];
    const float* Wq    = (const float*)d_in[1];
    const float* bq    = (const float*)d_in[2];
    const float* Wk    = (const float*)d_in[3];
    const float* bk    = (const float*)d_in[4];
    const float* Wv    = (const float*)d_in[5];
    const float* bv    = (const float*)d_in[6];
    const float* Wo    = (const float*)d_in[7];
    const float* bo    = (const float*)d_in[8];
    const float* coeff = (const float*)d_in[9];
    const float* scale = (const float*)d_in[10];
    float* out = (float*)d_out;

    size_t o = 0;
    char* w = (char*)d_ws;
    auto take = [&](size_t bytes) -> void* {
        void* p = w + o; o += (bytes + 255) & ~(size_t)255; return p;
    };
    int*    coo_cnt = (int*)take(4);
    int*    coo_m   = (int*)take(MAXNNZ * 4);
    int*    coo_p   = (int*)take(MAXNNZ * 4);
    float*  coo_v   = (float*)take(MAXNNZ * 4);
    int*    csc_ptr = (int*)take(257 * 4);
    int*    csc_m   = (int*)take(MAXNNZ * 4);
    float*  csc_v   = (float*)take(MAXNNZ * 4);
    ushort* wqkv = (ushort*)take(6144L * 512 * 2);       // [wq;wk;wv] stacked
    ushort* wob  = (ushort*)take(2048L * 2048 * 2);
    ushort* xT   = (ushort*)take(32L * 256 * 512 * 2);   // [b][n][cin] == [8192][512]
    ushort* qkv  = (ushort*)take(3 * 16777216L * 2);     // qbT | kbT | vb contiguous
    ushort* qbT = qkv;                                   // [b][h][n][d]
    ushort* kbT = qkv + 16777216L;                       // [b][h][m][d]
    ushort* vb  = qkv + 33554432L;                       // [b][2048][256]
    ushort* ktc = (ushort*)take(16777216L * 2);          // [z][p][d]
    // alias: kbT dead after kcomb -> obT lives there (disjoint from qbT/vb/ktc reads)
    ushort* obT  = kbT;                                  // [8192][2048]
    (void)in_sizes; (void)n_in; (void)out_size; (void)ws_size;

    // 1) sparsity structure
    hipMemsetAsync(coo_cnt, 0, 4, stream);
    topk_kernel<<<256, 256, 0, stream>>>(coeff, coo_cnt, coo_m, coo_p, coo_v);
    csc_kernel<<<1, 256, 0, stream>>>(coo_cnt, coo_m, coo_p, coo_v, csc_ptr, csc_m, csc_v);

    // 2) weight converts + x transpose
    cvt4_kernel<<<dim3(1024, 4, 1), 256, 0, stream>>>(
        Wq, wqkv, 2048 * 512, Wk, wqkv + 2048L * 512, 2048 * 512,
        Wv, wqkv + 4096L * 512, 2048 * 512, Wo, wob, 2048 * 2048);
    transpose_f32_bf16<<<dim3(8, 4, 32), 256, 0, stream>>>(x, xT, 512, 256);

    // 3) merged QKV projection: [6144,512] x [8192,512]^T, 256^2 pipelined tiles
    gemm256<4><<<dim3(768, 1, 1), dim3(512, 1, 1), 0, stream>>>(
        wqkv, xT, qkv, bq, bk, bv, 24, 512);

    // 4) K-combine with sparse coeff: ktc[z][p][d]
    kcomb_kernel<<<dim3(4, 256), 256, 0, stream>>>(kbT, ktc, csc_ptr, csc_m, csc_v);

    // 5+6) fused attention: softmax(Q^T K~ / s) V -> obT [8192][2048]
    attn_kernel<<<256, 512, 0, stream>>>(qbT, ktc, vb, obT, scale);

    // 7) merged final projection: [2048,2048] x [8192,2048]^T -> out f32 [b][2048][256]
    gemm256<5><<<dim3(256, 1, 1), dim3(512, 1, 1), 0, stream>>>(
        wob, obT, out, bo, nullptr, nullptr, 8, 2048);
}